// Round 2
// baseline (261.963 us; speedup 1.0000x reference)
//
#include <hip/hip_runtime.h>
#include <hip/hip_bf16.h>

// QLinear: per-row absmax int8 quant -> int8 GEMM (MFMA) -> fused dequant.
// M=8192, N=4096, K=4096 (derived from in_sizes at launch).

using int32x4 = __attribute__((ext_vector_type(4))) int;

#define QMAXF 127.0f

// ---------------------------------------------------------------------------
// Kernel 0: weight repack. The harness marshals integer inputs as int32
// ("integer -> const int*"), but may pass packed int8. Self-detect: probe the
// first 16 words as int32 -- all in [-127,127] <=> int32 encoding (prob of
// false positive on packed int8 data ~2^-380). Output: packed int8 in ws.
// ---------------------------------------------------------------------------
__global__ __launch_bounds__(256) void repack_weights(
    const int* __restrict__ w, signed char* __restrict__ w8, int total)
{
    bool is32 = true;
#pragma unroll
    for (int i = 0; i < 16; ++i) {
        int v = w[i];
        is32 = is32 && (v >= -127 && v <= 127);
    }

    const int t = blockIdx.x * blockDim.x + threadIdx.x;
    const int nth = gridDim.x * blockDim.x;
    const int chunks = total / 16;          // 16 output bytes per chunk

    if (is32) {
        // int32-encoded: 16 ints (64 B) -> 16 bytes
        for (int c = t; c < chunks; c += nth) {
            const int32x4* src = reinterpret_cast<const int32x4*>(w + (size_t)c * 16);
            int32x4 a0 = src[0], a1 = src[1], a2 = src[2], a3 = src[3];
            int32x4 o;
            o[0] = (a0[0] & 0xff) | ((a0[1] & 0xff) << 8) | ((a0[2] & 0xff) << 16) | ((a0[3] & 0xff) << 24);
            o[1] = (a1[0] & 0xff) | ((a1[1] & 0xff) << 8) | ((a1[2] & 0xff) << 16) | ((a1[3] & 0xff) << 24);
            o[2] = (a2[0] & 0xff) | ((a2[1] & 0xff) << 8) | ((a2[2] & 0xff) << 16) | ((a2[3] & 0xff) << 24);
            o[3] = (a3[0] & 0xff) | ((a3[1] & 0xff) << 8) | ((a3[2] & 0xff) << 16) | ((a3[3] & 0xff) << 24);
            reinterpret_cast<int32x4*>(w8)[c] = o;
        }
    } else {
        // already packed int8: straight copy
        const int32x4* src = reinterpret_cast<const int32x4*>(w);
        int32x4* dst = reinterpret_cast<int32x4*>(w8);
        for (int c = t; c < chunks; c += nth) dst[c] = src[c];
    }
}

// ---------------------------------------------------------------------------
// Kernel 1: per-row absmax quantization. One block (256 thr) per row, K=4096.
// Each thread holds 16 floats (4x float4) -> single global read of x.
// ---------------------------------------------------------------------------
__global__ __launch_bounds__(256) void quant_rows(
    const float* __restrict__ x, signed char* __restrict__ q,
    float* __restrict__ scale, int K)
{
    const int row = blockIdx.x;
    const int t = threadIdx.x;
    const float4* xr = reinterpret_cast<const float4*>(x + (size_t)row * K);

    float4 v[4];
    float m = 0.f;
#pragma unroll
    for (int i = 0; i < 4; ++i) {
        v[i] = xr[t + i * 256];
        m = fmaxf(m, fmaxf(fmaxf(fabsf(v[i].x), fabsf(v[i].y)),
                           fmaxf(fabsf(v[i].z), fabsf(v[i].w))));
    }
    // wave (64-lane) butterfly max
#pragma unroll
    for (int off = 32; off >= 1; off >>= 1)
        m = fmaxf(m, __shfl_xor(m, off, 64));
    __shared__ float wmax[4];
    const int wave = t >> 6;
    if ((t & 63) == 0) wmax[wave] = m;
    __syncthreads();
    m = fmaxf(fmaxf(wmax[0], wmax[1]), fmaxf(wmax[2], wmax[3]));

    const float s   = m / QMAXF;                    // a_scale
    const float inv = (m > 0.f) ? (QMAXF / m) : 0.f;
    if (t == 0) scale[row] = s;

    int* qr = reinterpret_cast<int*>(q + (size_t)row * K);
#pragma unroll
    for (int i = 0; i < 4; ++i) {
        const float* f = reinterpret_cast<const float*>(&v[i]);
        unsigned int packed = 0;
#pragma unroll
        for (int j = 0; j < 4; ++j) {
            int qi = __float2int_rn(f[j] * inv);    // round-to-nearest-even
            qi = qi > 127 ? 127 : (qi < -127 ? -127 : qi);
            packed |= ((unsigned int)(qi & 0xff)) << (8 * j);
        }
        qr[t + i * 256] = (int)packed;
    }
}

// ---------------------------------------------------------------------------
// Kernel 2: int8 GEMM with fused dequant epilogue.
// C[m][n] = (sum_k qinp[m][k]*qweight[n][k]) * a_scale[m] * wparams[n] + bias[n]
// 128x128 tile, BK=64, 4 waves (2x2), mfma_i32_16x16x64_i8.
// ---------------------------------------------------------------------------
#define BM 128
#define BN 128
#define BK 64

__device__ __forceinline__ void async_copy16(const void* g, void* lds) {
    __builtin_amdgcn_global_load_lds(
        (const __attribute__((address_space(1))) void*)g,
        (__attribute__((address_space(3))) void*)lds, 16, 0, 0);
}

__global__ __launch_bounds__(256) void gemm_i8_dequant(
    const signed char* __restrict__ A,   // [M,K] qinp
    const signed char* __restrict__ B,   // [N,K] qweight (packed int8)
    const float* __restrict__ a_scale,   // [M]
    const float* __restrict__ wparams,   // [N]
    const float* __restrict__ bias,      // [N]
    float* __restrict__ out,             // [M,N]
    int M, int N, int K)
{
    __shared__ __align__(16) signed char As[BM * BK];  // 8 KB, linear [row][64]
    __shared__ __align__(16) signed char Bs[BN * BK];  // 8 KB, linear [col][64]

    const int t    = threadIdx.x;
    const int lane = t & 63;
    const int wave = t >> 6;
    const int wr   = wave >> 1;          // 0..1 (M direction)
    const int wc   = wave & 1;           // 0..1 (N direction)

    const int rowBase = blockIdx.y * BM;
    const int colBase = blockIdx.x * BN;

    int32x4 acc[4][4] = {};

    const int fr = lane & 15;            // fragment row/col within 16
    const int ks = lane >> 4;            // k-slot 0..3 (16 int8 each)

    for (int kt = 0; kt < K; kt += BK) {
        // ---- stage A and B tiles: 8 KB each, 2 issues x 256 thr x 16 B ----
#pragma unroll
        for (int j = 0; j < 2; ++j) {
            const int lin = j * 4096 + t * 16;
            const int rr  = lin >> 6;    // 0..127
            const int cc  = lin & 63;
            const signed char* gA = A + (size_t)(rowBase + rr) * K + kt + cc;
            const signed char* gB = B + (size_t)(colBase + rr) * K + kt + cc;
            // wave-uniform LDS base; HW writes base + lane*16
            char* ldsA = (char*)As + j * 4096 + wave * 1024;
            char* ldsB = (char*)Bs + j * 4096 + wave * 1024;
            async_copy16(gA, ldsA);
            async_copy16(gB, ldsB);
        }
        __syncthreads();   // compiler emits s_waitcnt vmcnt(0) before barrier

        // ---- fragments + MFMA ----
        int32x4 af[4], bf[4];
#pragma unroll
        for (int mm = 0; mm < 4; ++mm)
            af[mm] = *reinterpret_cast<const int32x4*>(
                As + (wr * 64 + mm * 16 + fr) * 64 + ks * 16);
#pragma unroll
        for (int nn = 0; nn < 4; ++nn)
            bf[nn] = *reinterpret_cast<const int32x4*>(
                Bs + (wc * 64 + nn * 16 + fr) * 64 + ks * 16);
#pragma unroll
        for (int mm = 0; mm < 4; ++mm)
#pragma unroll
            for (int nn = 0; nn < 4; ++nn)
                acc[mm][nn] = __builtin_amdgcn_mfma_i32_16x16x64_i8(
                    af[mm], bf[nn], acc[mm][nn], 0, 0, 0);
        __syncthreads();
    }

    // ---- epilogue: dequant + bias. C/D map: col=lane&15, row=(lane>>4)*4+r
    const int rq = lane >> 4;
#pragma unroll
    for (int nn = 0; nn < 4; ++nn) {
        const int col = colBase + wc * 64 + nn * 16 + fr;
        const float wp = wparams[col];
        const float bs = bias[col];
#pragma unroll
        for (int mm = 0; mm < 4; ++mm) {
            const int rbase = rowBase + wr * 64 + mm * 16 + rq * 4;
#pragma unroll
            for (int r = 0; r < 4; ++r) {
                const int row = rbase + r;
                const float v = (float)acc[mm][nn][r] * a_scale[row] * wp + bs;
                out[(size_t)row * N + col] = v;
            }
        }
    }
}

// ---------------------------------------------------------------------------
extern "C" void kernel_launch(void* const* d_in, const int* in_sizes, int n_in,
                              void* d_out, int out_size, void* d_ws, size_t ws_size,
                              hipStream_t stream) {
    const float* inp     = (const float*)d_in[0];
    const int*   qw_raw  = (const int*)d_in[1];      // int8 weights, possibly int32-marshalled
    const float* wparams = (const float*)d_in[2];
    const float* bias    = (const float*)d_in[3];
    float*       out     = (float*)d_out;

    const int N = in_sizes[2];             // 4096
    const int K = in_sizes[1] / N;         // 4096
    const int M = in_sizes[0] / K;         // 8192

    // workspace layout: qinp [M*K B] | a_scale [M*4 B] | w8 [N*K B]
    signed char* qinp    = (signed char*)d_ws;
    float*       a_scale = (float*)((char*)d_ws + (size_t)M * K);
    size_t off_w8 = (size_t)M * K + (((size_t)M * sizeof(float) + 255) & ~(size_t)255);
    signed char* w8      = (signed char*)((char*)d_ws + off_w8);

    repack_weights<<<2048, 256, 0, stream>>>(qw_raw, w8, N * K);
    quant_rows<<<M, 256, 0, stream>>>(inp, qinp, a_scale, K);

    dim3 grid(N / BN, M / BM);
    gemm_i8_dequant<<<grid, dim3(256), 0, stream>>>(
        qinp, w8, a_scale, wparams, bias, out, M, N, K);
}

// Round 3
// 213.913 us; speedup vs baseline: 1.2246x; 1.2246x over previous
//
#include <hip/hip_runtime.h>
#include <hip/hip_bf16.h>

// QLinear: per-row absmax int8 quant -> int8 GEMM (MFMA) -> fused dequant.
// M=8192, N=4096, K=4096 (derived from in_sizes at launch).

using int32x4 = __attribute__((ext_vector_type(4))) int;

#define QMAXF 127.0f

// ---------------------------------------------------------------------------
// Kernel 0: weight repack (int32-marshalled int8 -> packed int8). Self-detects
// encoding by probing the first 16 words.
// ---------------------------------------------------------------------------
__global__ __launch_bounds__(256) void repack_weights(
    const int* __restrict__ w, signed char* __restrict__ w8, int total)
{
    bool is32 = true;
#pragma unroll
    for (int i = 0; i < 16; ++i) {
        int v = w[i];
        is32 = is32 && (v >= -127 && v <= 127);
    }

    const int t = blockIdx.x * blockDim.x + threadIdx.x;
    const int nth = gridDim.x * blockDim.x;
    const int chunks = total / 16;

    if (is32) {
        for (int c = t; c < chunks; c += nth) {
            const int32x4* src = reinterpret_cast<const int32x4*>(w + (size_t)c * 16);
            int32x4 a0 = src[0], a1 = src[1], a2 = src[2], a3 = src[3];
            int32x4 o;
            o[0] = (a0[0] & 0xff) | ((a0[1] & 0xff) << 8) | ((a0[2] & 0xff) << 16) | ((a0[3] & 0xff) << 24);
            o[1] = (a1[0] & 0xff) | ((a1[1] & 0xff) << 8) | ((a1[2] & 0xff) << 16) | ((a1[3] & 0xff) << 24);
            o[2] = (a2[0] & 0xff) | ((a2[1] & 0xff) << 8) | ((a2[2] & 0xff) << 16) | ((a2[3] & 0xff) << 24);
            o[3] = (a3[0] & 0xff) | ((a3[1] & 0xff) << 8) | ((a3[2] & 0xff) << 16) | ((a3[3] & 0xff) << 24);
            reinterpret_cast<int32x4*>(w8)[c] = o;
        }
    } else {
        const int32x4* src = reinterpret_cast<const int32x4*>(w);
        int32x4* dst = reinterpret_cast<int32x4*>(w8);
        for (int c = t; c < chunks; c += nth) dst[c] = src[c];
    }
}

// ---------------------------------------------------------------------------
// Kernel 1: per-row absmax quantization. One block (256 thr) per row, K=4096.
// ---------------------------------------------------------------------------
__global__ __launch_bounds__(256) void quant_rows(
    const float* __restrict__ x, signed char* __restrict__ q,
    float* __restrict__ scale, int K)
{
    const int row = blockIdx.x;
    const int t = threadIdx.x;
    const float4* xr = reinterpret_cast<const float4*>(x + (size_t)row * K);

    float4 v[4];
    float m = 0.f;
#pragma unroll
    for (int i = 0; i < 4; ++i) {
        v[i] = xr[t + i * 256];
        m = fmaxf(m, fmaxf(fmaxf(fabsf(v[i].x), fabsf(v[i].y)),
                           fmaxf(fabsf(v[i].z), fabsf(v[i].w))));
    }
#pragma unroll
    for (int off = 32; off >= 1; off >>= 1)
        m = fmaxf(m, __shfl_xor(m, off, 64));
    __shared__ float wmax[4];
    const int wave = t >> 6;
    if ((t & 63) == 0) wmax[wave] = m;
    __syncthreads();
    m = fmaxf(fmaxf(wmax[0], wmax[1]), fmaxf(wmax[2], wmax[3]));

    const float s   = m / QMAXF;
    const float inv = (m > 0.f) ? (QMAXF / m) : 0.f;
    if (t == 0) scale[row] = s;

    int* qr = reinterpret_cast<int*>(q + (size_t)row * K);
#pragma unroll
    for (int i = 0; i < 4; ++i) {
        const float* f = reinterpret_cast<const float*>(&v[i]);
        unsigned int packed = 0;
#pragma unroll
        for (int j = 0; j < 4; ++j) {
            int qi = __float2int_rn(f[j] * inv);
            qi = qi > 127 ? 127 : (qi < -127 ? -127 : qi);
            packed |= ((unsigned int)(qi & 0xff)) << (8 * j);
        }
        qr[t + i * 256] = (int)packed;
    }
}

// ---------------------------------------------------------------------------
// Kernel 2: int8 GEMM, 256x256 tile, 8 waves (2Mx4N), BK=128 bytes,
// double-buffered 2-phase schedule, fragment-order (conflict-free) LDS.
//
// LDS layout per buffer: A[32KB] | B[32KB]; each operand = 16 row-groups x
// 2 k-slices of 1KB fragment-tiles. Fragment-tile fi=(rg*2+sl) holds the
// exact MFMA operand for rows [rg*16,rg*16+16) x k-bytes [sl*64,sl*64+64),
// stored lane-linear: lane l's 16B at fi*1024 + l*16. global_load_lds writes
// wave-uniform-base + lane*16, so we pick the per-lane GLOBAL address to be
// row rg*16+(l&15), col sl*64+(l>>4)*16 -> ds_read_b128 at base+lane*16 is
// fully linear = zero bank conflicts (rule #21 via source permutation).
// ---------------------------------------------------------------------------
#define BM 256
#define BN 256
#define BKB 128

__device__ __forceinline__ void async_copy16(const void* g, void* lds) {
    __builtin_amdgcn_global_load_lds(
        (const __attribute__((address_space(1))) void*)g,
        (__attribute__((address_space(3))) void*)lds, 16, 0, 0);
}

__global__ __launch_bounds__(512, 2) void gemm_i8_dequant_256(
    const signed char* __restrict__ A,   // [M,K] qinp
    const signed char* __restrict__ B,   // [N,K] qweight (packed int8)
    const float* __restrict__ a_scale,   // [M]
    const float* __restrict__ wparams,   // [N]
    const float* __restrict__ bias,      // [N]
    float* __restrict__ out,             // [M,N]
    int M, int N, int K)
{
    __shared__ __align__(16) signed char lds[2 * 65536];   // 128 KiB

    const int t    = threadIdx.x;
    const int lane = t & 63;
    const int wave = t >> 6;           // 0..7
    const int wr   = wave >> 2;        // 0..1 (M half)
    const int wc   = wave & 3;         // 0..3 (N quarter)

    // T1: XCD-aware bijective swizzle (nwg % 8 == 0)
    const int nwg = gridDim.x;
    const int cpx = nwg >> 3;
    const int swz = (blockIdx.x & 7) * cpx + (blockIdx.x >> 3);
    const int nbx = N / BN;
    const int rowBase = (swz / nbx) * BM;
    const int colBase = (swz % nbx) * BN;

    const int r15 = lane & 15;
    const int ksl = lane >> 4;

    int32x4 acc[8][4] = {};

    const int NT = K / BKB;            // 32

    auto stage = [&](int kt, int d) {
        signed char* base = lds + d * 65536;
#pragma unroll
        for (int j = 0; j < 4; ++j) {
            const int fi = j * 8 + wave;       // 0..31, wave-uniform
            const int rg = fi >> 1, sl = fi & 1;
            const size_t coff = (size_t)kt + sl * 64 + ksl * 16;
            const signed char* gA = A + (size_t)(rowBase + rg * 16 + r15) * K + coff;
            const signed char* gB = B + (size_t)(colBase + rg * 16 + r15) * K + coff;
            async_copy16(gA, base + fi * 1024);
            async_copy16(gB, base + 32768 + fi * 1024);
        }
    };

    auto compute = [&](int d) {
        const signed char* Ab = lds + d * 65536;
        const signed char* Bb = Ab + 32768;
#pragma unroll
        for (int sl = 0; sl < 2; ++sl) {
            int32x4 af[8], bf[4];
#pragma unroll
            for (int mm = 0; mm < 8; ++mm)
                af[mm] = *reinterpret_cast<const int32x4*>(
                    Ab + ((wr * 8 + mm) * 2 + sl) * 1024 + lane * 16);
#pragma unroll
            for (int nn = 0; nn < 4; ++nn)
                bf[nn] = *reinterpret_cast<const int32x4*>(
                    Bb + ((wc * 4 + nn) * 2 + sl) * 1024 + lane * 16);
            __builtin_amdgcn_s_setprio(1);
#pragma unroll
            for (int mm = 0; mm < 8; ++mm)
#pragma unroll
                for (int nn = 0; nn < 4; ++nn)
                    acc[mm][nn] = __builtin_amdgcn_mfma_i32_16x16x64_i8(
                        af[mm], bf[nn], acc[mm][nn], 0, 0, 0);
            __builtin_amdgcn_s_setprio(0);
        }
    };

    // ---- 2-phase pipeline: prefetch t+1 before computing t (T3 minimum) ----
    stage(0, 0);
    __syncthreads();                   // drains vmcnt(0): tile 0 landed
    int cur = 0;
    for (int tt = 0; tt < NT - 1; ++tt) {
        stage((tt + 1) * BKB, cur ^ 1);   // loads fly during MFMA below
        compute(cur);
        __syncthreads();               // vmcnt(0)+lgkmcnt(0): tile tt+1 ready
        cur ^= 1;
    }
    compute(cur);

    // ---- epilogue: dequant + bias. C/D map: col=lane&15, row=(lane>>4)*4+r
#pragma unroll
    for (int mm = 0; mm < 8; ++mm) {
        const int rb = rowBase + wr * 128 + mm * 16 + ksl * 4;
        float asc[4];
#pragma unroll
        for (int r = 0; r < 4; ++r) asc[r] = a_scale[rb + r];
#pragma unroll
        for (int nn = 0; nn < 4; ++nn) {
            const int col = colBase + wc * 64 + nn * 16 + r15;
            const float wp = wparams[col];
            const float bs = bias[col];
#pragma unroll
            for (int r = 0; r < 4; ++r) {
                out[(size_t)(rb + r) * N + col] =
                    (float)acc[mm][nn][r] * asc[r] * wp + bs;
            }
        }
    }
}

// ---------------------------------------------------------------------------
extern "C" void kernel_launch(void* const* d_in, const int* in_sizes, int n_in,
                              void* d_out, int out_size, void* d_ws, size_t ws_size,
                              hipStream_t stream) {
    const float* inp     = (const float*)d_in[0];
    const int*   qw_raw  = (const int*)d_in[1];
    const float* wparams = (const float*)d_in[2];
    const float* bias    = (const float*)d_in[3];
    float*       out     = (float*)d_out;

    const int N = in_sizes[2];             // 4096
    const int K = in_sizes[1] / N;         // 4096
    const int M = in_sizes[0] / K;         // 8192

    // workspace: qinp [M*K B] | a_scale [M*4 B, 256-pad] | w8 [N*K B]
    signed char* qinp    = (signed char*)d_ws;
    float*       a_scale = (float*)((char*)d_ws + (size_t)M * K);
    size_t off_w8 = (size_t)M * K + (((size_t)M * sizeof(float) + 255) & ~(size_t)255);
    signed char* w8      = (signed char*)((char*)d_ws + off_w8);

    repack_weights<<<2048, 256, 0, stream>>>(qw_raw, w8, N * K);
    quant_rows<<<M, 256, 0, stream>>>(inp, qinp, a_scale, K);

    const int nwg = (M / BM) * (N / BN);   // 32*16 = 512, %8 == 0
    gemm_i8_dequant_256<<<nwg, 512, 0, stream>>>(
        qinp, w8, a_scale, wparams, bias, out, M, N, K);
}

// Round 4
// 203.406 us; speedup vs baseline: 1.2879x; 1.0517x over previous
//
#include <hip/hip_runtime.h>
#include <hip/hip_bf16.h>

// QLinear: per-row absmax int8 quant -> int8 GEMM (MFMA) -> fused dequant.
// M=8192, S=2048*4, K=4096, N=4096 (derived from in_sizes at launch).

using int32x4 = __attribute__((ext_vector_type(4))) int;

#define QMAXF 127.0f

// ---------------------------------------------------------------------------
// Kernel 0: weight repack (int32-marshalled int8 -> packed int8). Self-detects
// encoding by probing the first 16 words.
// ---------------------------------------------------------------------------
__global__ __launch_bounds__(256) void repack_weights(
    const int* __restrict__ w, signed char* __restrict__ w8, int total)
{
    bool is32 = true;
#pragma unroll
    for (int i = 0; i < 16; ++i) {
        int v = w[i];
        is32 = is32 && (v >= -127 && v <= 127);
    }

    const int t = blockIdx.x * blockDim.x + threadIdx.x;
    const int nth = gridDim.x * blockDim.x;
    const int chunks = total / 16;

    if (is32) {
        for (int c = t; c < chunks; c += nth) {
            const int32x4* src = reinterpret_cast<const int32x4*>(w + (size_t)c * 16);
            int32x4 a0 = src[0], a1 = src[1], a2 = src[2], a3 = src[3];
            int32x4 o;
            o[0] = (a0[0] & 0xff) | ((a0[1] & 0xff) << 8) | ((a0[2] & 0xff) << 16) | ((a0[3] & 0xff) << 24);
            o[1] = (a1[0] & 0xff) | ((a1[1] & 0xff) << 8) | ((a1[2] & 0xff) << 16) | ((a1[3] & 0xff) << 24);
            o[2] = (a2[0] & 0xff) | ((a2[1] & 0xff) << 8) | ((a2[2] & 0xff) << 16) | ((a2[3] & 0xff) << 24);
            o[3] = (a3[0] & 0xff) | ((a3[1] & 0xff) << 8) | ((a3[2] & 0xff) << 16) | ((a3[3] & 0xff) << 24);
            reinterpret_cast<int32x4*>(w8)[c] = o;
        }
    } else {
        const int32x4* src = reinterpret_cast<const int32x4*>(w);
        int32x4* dst = reinterpret_cast<int32x4*>(w8);
        for (int c = t; c < chunks; c += nth) dst[c] = src[c];
    }
}

// ---------------------------------------------------------------------------
// Kernel 1: per-row absmax quantization. One block (256 thr) per row, K=4096.
// ---------------------------------------------------------------------------
__global__ __launch_bounds__(256) void quant_rows(
    const float* __restrict__ x, signed char* __restrict__ q,
    float* __restrict__ scale, int K)
{
    const int row = blockIdx.x;
    const int t = threadIdx.x;
    const float4* xr = reinterpret_cast<const float4*>(x + (size_t)row * K);

    float4 v[4];
    float m = 0.f;
#pragma unroll
    for (int i = 0; i < 4; ++i) {
        v[i] = xr[t + i * 256];
        m = fmaxf(m, fmaxf(fmaxf(fabsf(v[i].x), fabsf(v[i].y)),
                           fmaxf(fabsf(v[i].z), fabsf(v[i].w))));
    }
#pragma unroll
    for (int off = 32; off >= 1; off >>= 1)
        m = fmaxf(m, __shfl_xor(m, off, 64));
    __shared__ float wmax[4];
    const int wave = t >> 6;
    if ((t & 63) == 0) wmax[wave] = m;
    __syncthreads();
    m = fmaxf(fmaxf(wmax[0], wmax[1]), fmaxf(wmax[2], wmax[3]));

    const float s   = m / QMAXF;
    const float inv = (m > 0.f) ? (QMAXF / m) : 0.f;
    if (t == 0) scale[row] = s;

    int* qr = reinterpret_cast<int*>(q + (size_t)row * K);
#pragma unroll
    for (int i = 0; i < 4; ++i) {
        const float* f = reinterpret_cast<const float*>(&v[i]);
        unsigned int packed = 0;
#pragma unroll
        for (int j = 0; j < 4; ++j) {
            int qi = __float2int_rn(f[j] * inv);
            qi = qi > 127 ? 127 : (qi < -127 ? -127 : qi);
            packed |= ((unsigned int)(qi & 0xff)) << (8 * j);
        }
        qr[t + i * 256] = (int)packed;
    }
}

// ---------------------------------------------------------------------------
// Kernel 2: int8 GEMM, 256x256 tile, 8 waves (2Mx4N), K-step = 64 bytes,
// 4-buffer LDS, depth-3 prefetch with COUNTED vmcnt (T3+T4) + setprio (T5).
//
// Fragment-order LDS (zero bank conflicts): each 1 KB frag-tile fi holds the
// MFMA operand for rows [fi*16,fi*16+16) x 64 k-bytes, lane-linear (lane l's
// 16 B at fi*1024 + l*16). global_load_lds writes base + lane*16; per-lane
// GLOBAL addr is row fi*16+(l&15), kcol (l>>4)*16, so LDS reads at
// base + lane*16 are fully linear.
//
// Schedule per iteration t (buffers indexed t&3):
//   issue A-loads for tile t+3 -> ds_read af[0..3],bf -> 16 MFMA ->
//   issue B-loads for tile t+3 -> ds_read af[4..7]    -> 16 MFMA ->
//   s_waitcnt vmcnt(8)   (waits ONLY tile t+1's 4 loads; 8 stay in flight)
//   s_barrier            (raw: no compiler vmcnt(0) drain)
// Safety: every ds_read is consumed by an MFMA before the tile-end barrier
// (compiler-enforced lgkmcnt), so buf (t+3)&3 is reread-free when rewritten;
// its prior DMA writes completed >= 2 iterations ago per the vmcnt chain.
// ---------------------------------------------------------------------------
#define BM 256
#define BN 256
#define BKB 64
#define NBUF 4

__device__ __forceinline__ void async_copy16(const void* g, void* lds) {
    __builtin_amdgcn_global_load_lds(
        (const __attribute__((address_space(1))) void*)g,
        (__attribute__((address_space(3))) void*)lds, 16, 0, 0);
}

__global__ __launch_bounds__(512, 2) void gemm_i8_dequant_8ph(
    const signed char* __restrict__ A,   // [M,K] qinp
    const signed char* __restrict__ B,   // [N,K] qweight (packed int8)
    const float* __restrict__ a_scale,   // [M]
    const float* __restrict__ wparams,   // [N]
    const float* __restrict__ bias,      // [N]
    float* __restrict__ out,             // [M,N]
    int M, int N, int K)
{
    __shared__ __align__(16) signed char lds[NBUF * 32768];   // 128 KiB

    const int t    = threadIdx.x;
    const int lane = t & 63;
    const int wave = t >> 6;           // 0..7
    const int wr   = wave >> 2;        // 0..1 (M half)
    const int wc   = wave & 3;         // 0..3 (N quarter)

    // T1: XCD-aware bijective swizzle (nwg % 8 == 0)
    const int nwg = gridDim.x;
    const int cpx = nwg >> 3;
    const int swz = (blockIdx.x & 7) * cpx + (blockIdx.x >> 3);
    const int nbx = N / BN;
    const int rowBase = (swz / nbx) * BM;
    const int colBase = (swz % nbx) * BN;

    const int r15 = lane & 15;
    const int ksl = lane >> 4;

    int32x4 acc[8][4] = {};
    const int NT = K / BKB;            // 64

    // per-thread global staging addresses (frag fi = wave and fi = 8+wave)
    const signed char* gA0 = A + (size_t)(rowBase + wave * 16 + r15)       * K + ksl * 16;
    const signed char* gA1 = A + (size_t)(rowBase + (8 + wave) * 16 + r15) * K + ksl * 16;
    const signed char* gB0 = B + (size_t)(colBase + wave * 16 + r15)       * K + ksl * 16;
    const signed char* gB1 = B + (size_t)(colBase + (8 + wave) * 16 + r15) * K + ksl * 16;

    auto stageA = [&](int kt, int d) {
        signed char* L = lds + d * 32768;
        async_copy16(gA0 + kt, L + wave * 1024);
        async_copy16(gA1 + kt, L + (8 + wave) * 1024);
    };
    auto stageB = [&](int kt, int d) {
        signed char* L = lds + d * 32768 + 16384;
        async_copy16(gB0 + kt, L + wave * 1024);
        async_copy16(gB1 + kt, L + (8 + wave) * 1024);
    };

    // compute halves for the tile in buffer d; optional stage of tile tn
    auto computeTile = [&](int d, int tn, bool doStage) {
        const signed char* Ab = lds + d * 32768;
        const signed char* Bb = Ab + 16384;
        const int dn = tn & (NBUF - 1);

        if (doStage) stageA(tn * BKB, dn);
        int32x4 af[8], bf[4];
#pragma unroll
        for (int mm = 0; mm < 4; ++mm)
            af[mm] = *reinterpret_cast<const int32x4*>(
                Ab + (wr * 8 + mm) * 1024 + lane * 16);
#pragma unroll
        for (int nn = 0; nn < 4; ++nn)
            bf[nn] = *reinterpret_cast<const int32x4*>(
                Bb + (wc * 4 + nn) * 1024 + lane * 16);
        __builtin_amdgcn_s_setprio(1);
#pragma unroll
        for (int mm = 0; mm < 4; ++mm)
#pragma unroll
            for (int nn = 0; nn < 4; ++nn)
                acc[mm][nn] = __builtin_amdgcn_mfma_i32_16x16x64_i8(
                    af[mm], bf[nn], acc[mm][nn], 0, 0, 0);
        __builtin_amdgcn_s_setprio(0);

        if (doStage) stageB(tn * BKB, dn);
#pragma unroll
        for (int mm = 4; mm < 8; ++mm)
            af[mm] = *reinterpret_cast<const int32x4*>(
                Ab + (wr * 8 + mm) * 1024 + lane * 16);
        __builtin_amdgcn_s_setprio(1);
#pragma unroll
        for (int mm = 4; mm < 8; ++mm)
#pragma unroll
            for (int nn = 0; nn < 4; ++nn)
                acc[mm][nn] = __builtin_amdgcn_mfma_i32_16x16x64_i8(
                    af[mm], bf[nn], acc[mm][nn], 0, 0, 0);
        __builtin_amdgcn_s_setprio(0);
    };

    // ---- prologue: prefetch tiles 0,1,2 (12 loads in flight) ----
    stageA(0, 0);        stageB(0, 0);
    stageA(BKB, 1);      stageB(BKB, 1);
    stageA(2 * BKB, 2);  stageB(2 * BKB, 2);
    asm volatile("s_waitcnt vmcnt(8)" ::: "memory");   // tile 0 landed
    __builtin_amdgcn_s_barrier();

    // ---- steady state: t = 0 .. NT-4 ----
    for (int tt = 0; tt <= NT - 4; ++tt) {
        computeTile(tt & (NBUF - 1), tt + 3, true);
        asm volatile("s_waitcnt vmcnt(8)" ::: "memory"); // tile tt+1 landed
        __builtin_amdgcn_s_barrier();
    }
    // ---- tail ----
    computeTile((NT - 3) & (NBUF - 1), 0, false);
    asm volatile("s_waitcnt vmcnt(4)" ::: "memory");     // tile NT-2 landed
    __builtin_amdgcn_s_barrier();
    computeTile((NT - 2) & (NBUF - 1), 0, false);
    asm volatile("s_waitcnt vmcnt(0)" ::: "memory");     // tile NT-1 landed
    __builtin_amdgcn_s_barrier();
    computeTile((NT - 1) & (NBUF - 1), 0, false);

    // ---- epilogue: dequant + bias. C/D map: col=lane&15, row=(lane>>4)*4+r
#pragma unroll
    for (int mm = 0; mm < 8; ++mm) {
        const int rb = rowBase + wr * 128 + mm * 16 + ksl * 4;
        float asc[4];
#pragma unroll
        for (int r = 0; r < 4; ++r) asc[r] = a_scale[rb + r];
#pragma unroll
        for (int nn = 0; nn < 4; ++nn) {
            const int col = colBase + wc * 64 + nn * 16 + r15;
            const float wp = wparams[col];
            const float bs = bias[col];
#pragma unroll
            for (int r = 0; r < 4; ++r) {
                out[(size_t)(rb + r) * N + col] =
                    (float)acc[mm][nn][r] * asc[r] * wp + bs;
            }
        }
    }
}

// ---------------------------------------------------------------------------
extern "C" void kernel_launch(void* const* d_in, const int* in_sizes, int n_in,
                              void* d_out, int out_size, void* d_ws, size_t ws_size,
                              hipStream_t stream) {
    const float* inp     = (const float*)d_in[0];
    const int*   qw_raw  = (const int*)d_in[1];
    const float* wparams = (const float*)d_in[2];
    const float* bias    = (const float*)d_in[3];
    float*       out     = (float*)d_out;

    const int N = in_sizes[2];             // 4096
    const int K = in_sizes[1] / N;         // 4096
    const int M = in_sizes[0] / K;         // 8192

    // workspace: qinp [M*K B] | a_scale [M*4 B, 256-pad] | w8 [N*K B]
    signed char* qinp    = (signed char*)d_ws;
    float*       a_scale = (float*)((char*)d_ws + (size_t)M * K);
    size_t off_w8 = (size_t)M * K + (((size_t)M * sizeof(float) + 255) & ~(size_t)255);
    signed char* w8      = (signed char*)((char*)d_ws + off_w8);

    repack_weights<<<2048, 256, 0, stream>>>(qw_raw, w8, N * K);
    quant_rows<<<M, 256, 0, stream>>>(inp, qinp, a_scale, K);

    const int nwg = (M / BM) * (N / BN);   // 32*16 = 512, %8 == 0
    gemm_i8_dequant_8ph<<<nwg, 512, 0, stream>>>(
        qinp, w8, a_scale, wparams, bias, out, M, N, K);
}